// Round 10
// baseline (230.549 us; speedup 1.0000x reference)
//
#include <hip/hip_runtime.h>
#include <math.h>

#define BB 16
#define QQ 500
#define NN 128
#define KK2 34   // 17 keypoints * 2

// ---------------------------------------------------------------------------
// Kernel 1: cost matrix  C[b][q][n]  (fp32, exact op order of the reference)
// Optionally writes transposed copy as f32 (CTF) or widened f64 (CTD).
// Cost math UNCHANGED from the passing rounds (numerics must stay identical).
// ---------------------------------------------------------------------------
__global__ __launch_bounds__(128) void cost_kernel(
    const float* __restrict__ pb,   // (B,Q,4) cxcywh
    const float* __restrict__ pk,   // (B,Q,17,2)
    const float* __restrict__ tb,   // (B,N,4)
    const float* __restrict__ tk,   // (B,N,17,2)
    float* __restrict__ C,          // (B,Q,N)
    float* __restrict__ CTF,        // (B,N,Q) f32 or nullptr
    double* __restrict__ CTD,       // (B,N,Q) f64 or nullptr
    int wf32, int wf64)
{
#pragma clang fp contract(off)
    const int q = blockIdx.x;
    const int b = blockIdx.y;
    const int n = threadIdx.x;

    __shared__ float spb[4];
    __shared__ float spk[KK2];
    if (threadIdx.x < 4)
        spb[threadIdx.x] = pb[((size_t)b * QQ + q) * 4 + threadIdx.x];
    if (threadIdx.x < KK2)
        spk[threadIdx.x] = pk[((size_t)b * QQ + q) * KK2 + threadIdx.x];
    __syncthreads();

    const float pcx = spb[0], pcy = spb[1], pw = spb[2], ph = spb[3];

    const size_t tbase = ((size_t)b * NN + n) * 4;
    const float tcx = tb[tbase + 0];
    const float tcy = tb[tbase + 1];
    const float tw  = tb[tbase + 2];
    const float th  = tb[tbase + 3];

    float cb = fabsf(pcx - tcx);
    cb = cb + fabsf(pcy - tcy);
    cb = cb + fabsf(pw - tw);
    cb = cb + fabsf(ph - th);

    float px0 = pcx - 0.5f * pw;
    float py0 = pcy - 0.5f * ph;
    float px1 = pcx + 0.5f * pw;
    float py1 = pcy + 0.5f * ph;
    px1 = fmaxf(px1, px0 + 1e-4f);
    py1 = fmaxf(py1, py0 + 1e-4f);

    float tx0 = tcx - 0.5f * tw;
    float ty0 = tcy - 0.5f * th;
    float tx1 = tcx + 0.5f * tw;
    float ty1 = tcy + 0.5f * th;
    tx1 = fmaxf(tx1, tx0 + 1e-4f);
    ty1 = fmaxf(ty1, ty0 + 1e-4f);

    const float area_p = (px1 - px0) * (py1 - py0);
    const float area_t = (tx1 - tx0) * (ty1 - ty0);

    const float ltx = fmaxf(px0, tx0);
    const float lty = fmaxf(py0, ty0);
    const float rbx = fminf(px1, tx1);
    const float rby = fminf(py1, ty1);
    const float wx = fmaxf(rbx - ltx, 0.0f);
    const float wy = fmaxf(rby - lty, 0.0f);
    const float inter = wx * wy;
    const float uni = (area_p + area_t) - inter;
    const float iou = inter / uni;

    const float ex0 = fminf(px0, tx0);
    const float ey0 = fminf(py0, ty0);
    const float ex1 = fmaxf(px1, tx1);
    const float ey1 = fmaxf(py1, ty1);
    const float ewx = fmaxf(ex1 - ex0, 0.0f);
    const float ewy = fmaxf(ey1 - ey0, 0.0f);
    const float enc = ewx * ewy;

    const float giou = iou - (enc - uni) / enc;
    const float cg = -giou;

    const size_t kbase = ((size_t)b * NN + n) * KK2;
    float ck = 0.0f;
    for (int k = 0; k < KK2; ++k)
        ck = ck + fabsf(spk[k] - tk[kbase + k]);

    const float Cv = (5.0f * cb + 2.0f * cg) + ck;

    C[((size_t)b * QQ + q) * NN + n] = Cv;
    if (wf32)
        CTF[((size_t)b * NN + n) * QQ + q] = Cv;
    if (wf64)
        CTD[((size_t)b * NN + n) * QQ + q] = (double)Cv;
}

// uniform-lane readlane helpers (scalar pipe, no LDS)
__device__ __forceinline__ int rl_i(int v, int l) {
    return __builtin_amdgcn_readlane(v, l);
}
__device__ __forceinline__ double rl_d(double v, int l) {
    int lo = __builtin_amdgcn_readlane(__double2loint(v), l);
    int hi = __builtin_amdgcn_readlane(__double2hiint(v), l);
    return __hiloint2double(hi, lo);
}

// one DPP min step on f64 (two 32-bit dpp movs + v_min_f64)
template <int CTRL>
__device__ __forceinline__ double dpp_fmin_step(double x) {
    int lo = __double2loint(x);
    int hi = __double2hiint(x);
    int nlo = __builtin_amdgcn_update_dpp(lo, lo, CTRL, 0xF, 0xF, false);
    int nhi = __builtin_amdgcn_update_dpp(hi, hi, CTRL, 0xF, 0xF, false);
    return fmin(__hiloint2double(nhi, nlo), x);
}
#define ROW_SHR1  0x111
#define ROW_SHR2  0x112
#define ROW_SHR4  0x114
#define ROW_SHR8  0x118
#define ROW_BC15  0x142
#define ROW_BC31  0x143

__device__ __forceinline__ double dpp_fmin_wave(double x) {
    x = dpp_fmin_step<ROW_SHR1>(x);
    x = dpp_fmin_step<ROW_SHR2>(x);
    x = dpp_fmin_step<ROW_SHR4>(x);
    x = dpp_fmin_step<ROW_SHR8>(x);
    x = dpp_fmin_step<ROW_BC15>(x);
    x = dpp_fmin_step<ROW_BC31>(x);
    return x;   // lane 63 holds the wave min
}

// constant-index select/scatter on 8-arrays (register-resident, rule #20)
#define SEL8(arr, kq, out) do { \
    out = arr[0]; \
    if ((kq)==1) out = arr[1]; if ((kq)==2) out = arr[2]; if ((kq)==3) out = arr[3]; \
    if ((kq)==4) out = arr[4]; if ((kq)==5) out = arr[5]; if ((kq)==6) out = arr[6]; \
    if ((kq)==7) out = arr[7]; } while (0)

#define SCAT8(arr, kq, val) do { \
    if ((kq)==0) arr[0] = (val); if ((kq)==1) arr[1] = (val); \
    if ((kq)==2) arr[2] = (val); if ((kq)==3) arr[3] = (val); \
    if ((kq)==4) arr[4] = (val); if ((kq)==5) arr[5] = (val); \
    if ((kq)==6) arr[6] = (val); if ((kq)==7) arr[7] = (val); } while (0)

// ---------------------------------------------------------------------------
// Kernel 1.5a: per-row min+argmin of CTF (f32) rows -> packed f64(min)|idx.
// ---------------------------------------------------------------------------
__global__ __launch_bounds__(64) void rowmin32_kernel(
    const float* __restrict__ CTF,  // (B,N,Q)
    double* __restrict__ rm)        // (B,N)
{
    const int n = blockIdx.x;
    const int b = blockIdx.y;
    const int lane = threadIdx.x;

    const float4* r4 = reinterpret_cast<const float4*>(CTF + ((size_t)b * NN + n) * QQ);

    float m = INFINITY;
    int jm = 0;
    {
        float4 a = r4[lane];
        int base = lane * 4;
        if (a.x < m) { m = a.x; jm = base + 0; }
        if (a.y < m) { m = a.y; jm = base + 1; }
        if (a.z < m) { m = a.z; jm = base + 2; }
        if (a.w < m) { m = a.w; jm = base + 3; }
    }
    if (lane < 61) {
        float4 a = r4[64 + lane];
        int base = (64 + lane) * 4;
        if (a.x < m) { m = a.x; jm = base + 0; }
        if (a.y < m) { m = a.y; jm = base + 1; }
        if (a.z < m) { m = a.z; jm = base + 2; }
        if (a.w < m) { m = a.w; jm = base + 3; }
    }

    long long kb = __double_as_longlong((double)m) | (long long)jm;
    double kd = dpp_fmin_wave(__longlong_as_double(kb));
    if (lane == 63)
        rm[(size_t)b * NN + n] = kd;
}

// ---------------------------------------------------------------------------
// Kernel 1.5b: per-row min+argmin of CTD (f64) rows -> packed f64(min)|idx.
// CTD values are widened f32 (29 low mantissa bits zero) -> packing exact.
// Lane l owns elements 8l..8l+7 (same layout as the LSA kernel).
// ---------------------------------------------------------------------------
__global__ __launch_bounds__(64) void rowmin64_kernel(
    const double* __restrict__ CTD, // (B,N,Q)
    double* __restrict__ rm)        // (B,N)
{
    const int n = blockIdx.x;
    const int b = blockIdx.y;
    const int lane = threadIdx.x;

    const double2* r2 = reinterpret_cast<const double2*>(CTD + ((size_t)b * NN + n) * QQ);

    double m = INFINITY;
    int jm = 0;
#pragma unroll
    for (int t = 0; t < 4; ++t) {
        int j = lane * 8 + t * 2;
        if (j + 1 < QQ) {
            double2 a = r2[lane * 4 + t];
            if (a.x < m) { m = a.x; jm = j; }
            if (a.y < m) { m = a.y; jm = j + 1; }
        }
    }

    long long kb = __double_as_longlong(m) | (long long)jm;
    double kd = dpp_fmin_wave(__longlong_as_double(kb));
    if (lane == 63)
        rm[(size_t)b * NN + n] = kd;
}

// ---------------------------------------------------------------------------
// Kernel 2: per-batch rectangular LSA (JV / shortest augmenting path) on
// cost[b].T (N=128 rows x Q=500 cols). Row reduction + greedy init, then SAP.
// Round-6-validated algebra, issue-diet only:
//  - MODE 2: cost rows loaded as f64 (CTD) -> no per-step cvt ops.
//  - invalid columns filled with +INF: packed rp becomes NaN -> compare false,
//    removing all (k < nval) gates from the hot loops (proof: NaN < x false).
//  - no __syncthreads (single wave; LDS ordering via compiler waitcnt).
// ONE WAVE per batch. Lane l owns columns j = 8l..8l+7 and rows l, l+64.
// ---------------------------------------------------------------------------
template <int MODE, bool PRE>   // MODE: 0 = C strided f32, 1 = CTF f32, 2 = CTD f64
__global__ __launch_bounds__(64) void lsa_wave_kernel(
    const float* __restrict__ C,    // (B,Q,N)
    const float* __restrict__ CTF,  // (B,N,Q) or nullptr
    const double* __restrict__ CTD, // (B,N,Q) or nullptr
    const double* __restrict__ rm,  // (B,N) packed rowmin or nullptr
    float* __restrict__ out_rows,   // (B,N) as float
    float* __restrict__ out_cols)   // (B,N) as float
{
#pragma clang fp contract(off)
    const int b = blockIdx.x;
    const int lane = threadIdx.x;

    __shared__ double s_spc[64 * 10];   // stride 10 doubles (80 B) per lane
    __shared__ int s_q[NN];

    const float*  Cb   = C + (size_t)b * QQ * NN;
    const float*  CTFb = (MODE == 1) ? (CTF + (size_t)b * NN * QQ) : nullptr;
    const double* CTDb = (MODE == 2) ? (CTD + (size_t)b * NN * QQ) : nullptr;

    const int j0 = lane * 8;
    const int nval = (QQ - j0 < 0) ? 0 : ((QQ - j0 > 8) ? 8 : (QQ - j0));

    double v_[8], spc_[8];
    int path_[8], r4c_[8];
    double u0, u1;
    int c4r0 = -1, c4r1 = -1;
    int jm0, jm1;
#pragma unroll
    for (int k = 0; k < 8; ++k) { v_[k] = 0.0; r4c_[k] = -1; }

    // ---- Phase A: row minima (u) + L2 warm pass ----
    if (PRE) {
        const long long p0 = __double_as_longlong(rm[(size_t)b * NN + lane]);
        const long long p1 = __double_as_longlong(rm[(size_t)b * NN + 64 + lane]);
        u0 = __longlong_as_double(p0 & ~0x1FFLL);
        u1 = __longlong_as_double(p1 & ~0x1FFLL);
        jm0 = (int)(p0 & 0x1FF);
        jm1 = (int)(p1 & 0x1FF);
        if (MODE == 2) {
            const double2* w2 = reinterpret_cast<const double2*>(CTDb);
            double acc = 0.0;
            for (int t = lane; t < (NN * QQ) / 2; t += 64) {
                double2 a = w2[t];
                acc += a.x + a.y;
            }
            asm volatile("" :: "v"(acc));
        } else if (MODE == 1) {
            const float4* w4 = reinterpret_cast<const float4*>(CTFb);
            float4 acc; acc.x = acc.y = acc.z = acc.w = 0.0f;
#pragma unroll 8
            for (int t = lane; t < (NN * QQ) / 4; t += 64) {
                float4 a = w4[t];
                acc.x += a.x; acc.y += a.y; acc.z += a.z; acc.w += a.w;
            }
            asm volatile("" :: "v"(acc.x), "v"(acc.y), "v"(acc.z), "v"(acc.w));
        }
    } else {
        float m0 = INFINITY, m1 = INFINITY;
        jm0 = 0; jm1 = 0;
#pragma unroll 4
        for (int q = 0; q < QQ; ++q) {
            float a, c;
            if (MODE == 1) {
                a = CTFb[(size_t)lane * QQ + q];
                c = CTFb[(size_t)(64 + lane) * QQ + q];
            } else {
                a = Cb[(size_t)q * NN + lane];
                c = Cb[(size_t)q * NN + 64 + lane];
            }
            if (a < m0) { m0 = a; jm0 = q; }
            if (c < m1) { m1 = c; jm1 = q; }
        }
        u0 = (double)m0;
        u1 = (double)m1;
    }

    // ---- Phase B: greedy matching on row minima (sequential, uniform) ----
    for (int i = 0; i < NN; ++i) {
        int jm = (i < 64) ? rl_i(jm0, i) : rl_i(jm1, i - 64);
        int kq = jm & 7;
        int selr; SEL8(r4c_, kq, selr);
        int occ = rl_i(selr, jm >> 3);
        if (occ < 0) {
            if (lane == (jm >> 3)) { SCAT8(r4c_, kq, i); }
            if (i < 64) { if (lane == i) c4r0 = jm; }
            else        { if (lane == i - 64) c4r1 = jm; }
        }
    }

    // ---- Phase C: shortest augmenting path for the unmatched rows ----
    for (int cur = 0; cur < NN; ++cur) {
        int already = (cur < 64) ? rl_i(c4r0, cur) : rl_i(c4r1, cur - 64);
        if (already >= 0) continue;

        const double INF = INFINITY;
#pragma unroll
        for (int k = 0; k < 8; ++k) { spc_[k] = INF; path_[k] = -1; }
        unsigned int sc = 0;
        int sr0 = 0, sr1 = 0;
        double minv = 0.0;
        int i = cur, sink = -1;

        while (true) {
            // ---- cost row i, my 8 columns (invalid -> +INF) ----
            double c_[8];
            if (MODE == 2) {
                const double2* p = reinterpret_cast<const double2*>(CTDb + (size_t)i * QQ + j0);
                if (nval > 0) {
                    double2 a = p[0], b2 = p[1];
                    c_[0] = a.x; c_[1] = a.y; c_[2] = b2.x; c_[3] = b2.y;
                } else { c_[0] = c_[1] = c_[2] = c_[3] = INF; }
                if (nval > 4) {
                    double2 a = p[2], b2 = p[3];
                    c_[4] = a.x; c_[5] = a.y; c_[6] = b2.x; c_[7] = b2.y;
                } else { c_[4] = c_[5] = c_[6] = c_[7] = INF; }
            } else if (MODE == 1) {
                const float4* p = reinterpret_cast<const float4*>(CTFb + (size_t)i * QQ + j0);
                if (nval > 0) {
                    float4 a = p[0];
                    c_[0] = (double)a.x; c_[1] = (double)a.y;
                    c_[2] = (double)a.z; c_[3] = (double)a.w;
                } else { c_[0] = c_[1] = c_[2] = c_[3] = INF; }
                if (nval > 4) {
                    float4 a = p[1];
                    c_[4] = (double)a.x; c_[5] = (double)a.y;
                    c_[6] = (double)a.z; c_[7] = (double)a.w;
                } else { c_[4] = c_[5] = c_[6] = c_[7] = INF; }
            } else {
#pragma unroll
                for (int k = 0; k < 8; ++k)
                    c_[k] = (j0 + k < QQ) ? (double)Cb[(size_t)(j0 + k) * NN + i] : INF;
            }

            // SR[i] = True
            if (i < 64) { if (lane == i) sr0 = 1; }
            else        { if (lane == i - 64) sr1 = 1; }

            // u[i] broadcast — uniform i => readlane
            double ui = (i < 64) ? rl_d(u0, i) : rl_d(u1, i - 64);
            double s = minv - ui;   // wave-uniform

            // relax + pack column index into low mantissa bits.
            // invalid k: c=+INF -> rp is NaN -> compare false (no nval gate).
#pragma unroll
            for (int k = 0; k < 8; ++k) {
                double r = (s + c_[k]) - v_[k];
                long long rb = (__double_as_longlong(r) & ~0x1FFLL)
                             | (long long)(j0 + k);
                double rp = __longlong_as_double(rb);
                bool ok = !((sc >> k) & 1) && (rp < spc_[k]);
                if (ok) { spc_[k] = rp; path_[k] = i; }
            }

            // local min: mask SC -> inf + pure fmin tree (invalid spc stay INF)
            double val[8];
#pragma unroll
            for (int k = 0; k < 8; ++k)
                val[k] = ((sc >> k) & 1) ? INF : spc_[k];
            double t01 = fmin(val[0], val[1]);
            double t23 = fmin(val[2], val[3]);
            double t45 = fmin(val[4], val[5]);
            double t67 = fmin(val[6], val[7]);
            double lmin = fmin(fmin(t01, t23), fmin(t45, t67));

            // wave min via DPP chain; lane 63 holds global packed min
            double gk = rl_d(dpp_fmin_wave(lmin), 63);

            int jmin   = (int)(__double_as_longlong(gk) & 0x1FFLL);
            int winner = jmin >> 3;

            // SC[jmin] = True
            if (lane == winner) sc |= 1u << (jmin & 7);

            // r4 = row4col[jmin]  (uniform => readlane)
            int kq = jmin & 7;
            int selr; SEL8(r4c_, kq, selr);
            int r4 = rl_i(selr, winner);

            minv = gk;              // == spc[jmin] exactly (packed)
            if (r4 < 0) { sink = jmin; break; }
            i = r4;
        }

        // ---- spill spc to LDS for the col4row gather (single wave: no
        // barrier needed; compiler orders ds ops via lgkmcnt) ----
        {
            double* base = s_spc + lane * 10;
            double2 d01; d01.x = spc_[0]; d01.y = spc_[1];
            double2 d23; d23.x = spc_[2]; d23.y = spc_[3];
            double2 d45; d45.x = spc_[4]; d45.y = spc_[5];
            double2 d67; d67.x = spc_[6]; d67.y = spc_[7];
            *(double2*)(base + 0) = d01;
            *(double2*)(base + 2) = d23;
            *(double2*)(base + 4) = d45;
            *(double2*)(base + 6) = d67;
        }
        const int g0i = (c4r0 < 0) ? 0 : c4r0;
        const int g1i = (c4r1 < 0) ? 0 : c4r1;
        const double g0 = s_spc[(g0i >> 3) * 10 + (g0i & 7)];
        const double g1 = s_spc[(g1i >> 3) * 10 + (g1i & 7)];

        // ---- dual updates (pre-augmentation col4row) ----
        if (lane == cur) { u0 = u0 + minv; }
        else if (sr0)    { double t = minv - g0; u0 = u0 + t; }
        if (lane + 64 == cur) { u1 = u1 + minv; }
        else if (sr1)         { double t = minv - g1; u1 = u1 + t; }
#pragma unroll
        for (int k = 0; k < 8; ++k) {
            if ((sc >> k) & 1) {
                double t = minv - spc_[k];
                v_[k] = v_[k] - t;
            }
        }

        // ---- augment along alternating path (uniform j walk, readlane) ----
        int j = sink;
        while (true) {
            int kq = j & 7, src = j >> 3;
            int sp; SEL8(path_, kq, sp);
            int i2 = rl_i(sp, src);
            if (lane == src) { SCAT8(r4c_, kq, i2); }   // row4col[j] = i2
            int t2;
            if (i2 < 64) {
                t2 = rl_i(c4r0, i2);
                if (lane == i2) c4r0 = j;
            } else {
                t2 = rl_i(c4r1, i2 - 64);
                if (lane == i2 - 64) c4r1 = j;
            }
            j = t2;
            if (i2 == cur) break;
        }
    }

    // ---- output: rows = sorted assigned-query idx, cols = target idx ----
    s_q[lane] = c4r0;
    s_q[64 + lane] = c4r1;
    int rank0 = 0, rank1 = 0;
    for (int t = 0; t < NN; ++t) {
        int qv = s_q[t];
        rank0 += (qv < c4r0) ? 1 : 0;
        rank1 += (qv < c4r1) ? 1 : 0;
    }
    out_rows[(size_t)b * NN + rank0] = (float)c4r0;
    out_cols[(size_t)b * NN + rank0] = (float)lane;
    out_rows[(size_t)b * NN + rank1] = (float)c4r1;
    out_cols[(size_t)b * NN + rank1] = (float)(64 + lane);
}

// ---------------------------------------------------------------------------
extern "C" void kernel_launch(void* const* d_in, const int* in_sizes, int n_in,
                              void* d_out, int out_size, void* d_ws, size_t ws_size,
                              hipStream_t stream) {
    const float* pb = (const float*)d_in[0];  // pred_boxes     (B,Q,4)
    const float* pk = (const float*)d_in[1];  // pred_keypoints (B,Q,17,2)
    const float* tb = (const float*)d_in[2];  // tgt_boxes      (B,N,4)
    const float* tk = (const float*)d_in[3];  // tgt_keypoints  (B,N,17,2)

    float* outC  = (float*)d_out;                      // (B,Q,N)
    float* orows = outC + (size_t)BB * QQ * NN;        // (B,N)
    float* ocols = orows + (size_t)BB * NN;            // (B,N)

    const size_t ctd_bytes = (size_t)BB * NN * QQ * sizeof(double); // 8,192,000
    const size_t ctf_bytes = (size_t)BB * NN * QQ * sizeof(float);  // 4,096,000
    const size_t rm_bytes  = (size_t)BB * NN * sizeof(double);      //    16,384

    dim3 grid(QQ, BB);

    if (ws_size >= ctd_bytes + rm_bytes) {
        // f64 fast path: CTD + rowmin + SAP without cvt ops
        double* CTD = (double*)d_ws;
        double* RM  = (double*)((char*)d_ws + ctd_bytes);
        cost_kernel<<<grid, 128, 0, stream>>>(pb, pk, tb, tk, outC, nullptr, CTD, 0, 1);
        rowmin64_kernel<<<dim3(NN, BB), 64, 0, stream>>>(CTD, RM);
        lsa_wave_kernel<2, true><<<BB, 64, 0, stream>>>(outC, nullptr, CTD, RM, orows, ocols);
    } else if (ws_size >= ctf_bytes + rm_bytes) {
        float*  CTF = (float*)d_ws;
        double* RM  = (double*)((char*)d_ws + ctf_bytes);
        cost_kernel<<<grid, 128, 0, stream>>>(pb, pk, tb, tk, outC, CTF, nullptr, 1, 0);
        rowmin32_kernel<<<dim3(NN, BB), 64, 0, stream>>>(CTF, RM);
        lsa_wave_kernel<1, true><<<BB, 64, 0, stream>>>(outC, CTF, nullptr, RM, orows, ocols);
    } else if (ws_size >= ctf_bytes) {
        float* CTF = (float*)d_ws;
        cost_kernel<<<grid, 128, 0, stream>>>(pb, pk, tb, tk, outC, CTF, nullptr, 1, 0);
        lsa_wave_kernel<1, false><<<BB, 64, 0, stream>>>(outC, CTF, nullptr, nullptr, orows, ocols);
    } else {
        cost_kernel<<<grid, 128, 0, stream>>>(pb, pk, tb, tk, outC, nullptr, nullptr, 0, 0);
        lsa_wave_kernel<0, false><<<BB, 64, 0, stream>>>(outC, nullptr, nullptr, nullptr, orows, ocols);
    }
}

// Round 11
// 134.092 us; speedup vs baseline: 1.7193x; 1.7193x over previous
//
#include <hip/hip_runtime.h>
#include <math.h>

#define BB 16
#define QQ 500
#define NN 128
#define KK2 34   // 17 keypoints * 2

// ---------------------------------------------------------------------------
// Kernel 1: cost matrix  C[b][q][n]  (fp32, exact op order of the reference)
// Also writes transposed CT[b][n][q] (f32). UNCHANGED cost math.
// ---------------------------------------------------------------------------
__global__ __launch_bounds__(128) void cost_kernel(
    const float* __restrict__ pb,   // (B,Q,4) cxcywh
    const float* __restrict__ pk,   // (B,Q,17,2)
    const float* __restrict__ tb,   // (B,N,4)
    const float* __restrict__ tk,   // (B,N,17,2)
    float* __restrict__ C,          // (B,Q,N)
    float* __restrict__ CT,         // (B,N,Q) or nullptr
    int writeCT)
{
#pragma clang fp contract(off)
    const int q = blockIdx.x;
    const int b = blockIdx.y;
    const int n = threadIdx.x;

    __shared__ float spb[4];
    __shared__ float spk[KK2];
    if (threadIdx.x < 4)
        spb[threadIdx.x] = pb[((size_t)b * QQ + q) * 4 + threadIdx.x];
    if (threadIdx.x < KK2)
        spk[threadIdx.x] = pk[((size_t)b * QQ + q) * KK2 + threadIdx.x];
    __syncthreads();

    const float pcx = spb[0], pcy = spb[1], pw = spb[2], ph = spb[3];

    const size_t tbase = ((size_t)b * NN + n) * 4;
    const float tcx = tb[tbase + 0];
    const float tcy = tb[tbase + 1];
    const float tw  = tb[tbase + 2];
    const float th  = tb[tbase + 3];

    float cb = fabsf(pcx - tcx);
    cb = cb + fabsf(pcy - tcy);
    cb = cb + fabsf(pw - tw);
    cb = cb + fabsf(ph - th);

    float px0 = pcx - 0.5f * pw;
    float py0 = pcy - 0.5f * ph;
    float px1 = pcx + 0.5f * pw;
    float py1 = pcy + 0.5f * ph;
    px1 = fmaxf(px1, px0 + 1e-4f);
    py1 = fmaxf(py1, py0 + 1e-4f);

    float tx0 = tcx - 0.5f * tw;
    float ty0 = tcy - 0.5f * th;
    float tx1 = tcx + 0.5f * tw;
    float ty1 = tcy + 0.5f * th;
    tx1 = fmaxf(tx1, tx0 + 1e-4f);
    ty1 = fmaxf(ty1, ty0 + 1e-4f);

    const float area_p = (px1 - px0) * (py1 - py0);
    const float area_t = (tx1 - tx0) * (ty1 - ty0);

    const float ltx = fmaxf(px0, tx0);
    const float lty = fmaxf(py0, ty0);
    const float rbx = fminf(px1, tx1);
    const float rby = fminf(py1, ty1);
    const float wx = fmaxf(rbx - ltx, 0.0f);
    const float wy = fmaxf(rby - lty, 0.0f);
    const float inter = wx * wy;
    const float uni = (area_p + area_t) - inter;
    const float iou = inter / uni;

    const float ex0 = fminf(px0, tx0);
    const float ey0 = fminf(py0, ty0);
    const float ex1 = fmaxf(px1, tx1);
    const float ey1 = fmaxf(py1, ty1);
    const float ewx = fmaxf(ex1 - ex0, 0.0f);
    const float ewy = fmaxf(ey1 - ey0, 0.0f);
    const float enc = ewx * ewy;

    const float giou = iou - (enc - uni) / enc;
    const float cg = -giou;

    const size_t kbase = ((size_t)b * NN + n) * KK2;
    float ck = 0.0f;
    for (int k = 0; k < KK2; ++k)
        ck = ck + fabsf(spk[k] - tk[kbase + k]);

    const float Cv = (5.0f * cb + 2.0f * cg) + ck;

    C[((size_t)b * QQ + q) * NN + n] = Cv;
    if (writeCT)
        CT[((size_t)b * NN + n) * QQ + q] = Cv;
}

// uniform-lane readlane helpers (scalar pipe, no LDS)
__device__ __forceinline__ int rl_i(int v, int l) {
    return __builtin_amdgcn_readlane(v, l);
}
__device__ __forceinline__ double rl_d(double v, int l) {
    int lo = __builtin_amdgcn_readlane(__double2loint(v), l);
    int hi = __builtin_amdgcn_readlane(__double2hiint(v), l);
    return __hiloint2double(hi, lo);
}

// one DPP min step on f64 (two 32-bit dpp movs + v_min_f64)
template <int CTRL>
__device__ __forceinline__ double dpp_fmin_step(double x) {
    int lo = __double2loint(x);
    int hi = __double2hiint(x);
    int nlo = __builtin_amdgcn_update_dpp(lo, lo, CTRL, 0xF, 0xF, false);
    int nhi = __builtin_amdgcn_update_dpp(hi, hi, CTRL, 0xF, 0xF, false);
    return fmin(__hiloint2double(nhi, nlo), x);
}
#define ROW_SHR1  0x111
#define ROW_SHR2  0x112
#define ROW_SHR4  0x114
#define ROW_SHR8  0x118
#define ROW_BC15  0x142
#define ROW_BC31  0x143

__device__ __forceinline__ double dpp_fmin_wave(double x) {
    x = dpp_fmin_step<ROW_SHR1>(x);
    x = dpp_fmin_step<ROW_SHR2>(x);
    x = dpp_fmin_step<ROW_SHR4>(x);
    x = dpp_fmin_step<ROW_SHR8>(x);
    x = dpp_fmin_step<ROW_BC15>(x);
    x = dpp_fmin_step<ROW_BC31>(x);
    return x;   // lane 63 holds the wave min
}

// constant-index select/scatter on 8-arrays (register-resident, rule #20)
#define SEL8(arr, kq, out) do { \
    out = arr[0]; \
    if ((kq)==1) out = arr[1]; if ((kq)==2) out = arr[2]; if ((kq)==3) out = arr[3]; \
    if ((kq)==4) out = arr[4]; if ((kq)==5) out = arr[5]; if ((kq)==6) out = arr[6]; \
    if ((kq)==7) out = arr[7]; } while (0)

#define SCAT8(arr, kq, val) do { \
    if ((kq)==0) arr[0] = (val); if ((kq)==1) arr[1] = (val); \
    if ((kq)==2) arr[2] = (val); if ((kq)==3) arr[3] = (val); \
    if ((kq)==4) arr[4] = (val); if ((kq)==5) arr[5] = (val); \
    if ((kq)==6) arr[6] = (val); if ((kq)==7) arr[7] = (val); } while (0)

// ---------------------------------------------------------------------------
// Kernel 1.5: per-row min + first-occurrence argmin of CT rows.
// One block (64 lanes) per (row, batch). Packs exact f64(min)|9-bit-index
// (f32->f64 leaves 29 zero mantissa bits; mask recovers u exactly).
// ---------------------------------------------------------------------------
__global__ __launch_bounds__(64) void rowmin_kernel(
    const float* __restrict__ CT,   // (B,N,Q)
    double* __restrict__ rm)        // (B,N)
{
    const int n = blockIdx.x;
    const int b = blockIdx.y;
    const int lane = threadIdx.x;

    const float4* r4 = reinterpret_cast<const float4*>(CT + ((size_t)b * NN + n) * QQ);

    float m = INFINITY;
    int jm = 0;
    {
        float4 a = r4[lane];
        int base = lane * 4;
        if (a.x < m) { m = a.x; jm = base + 0; }
        if (a.y < m) { m = a.y; jm = base + 1; }
        if (a.z < m) { m = a.z; jm = base + 2; }
        if (a.w < m) { m = a.w; jm = base + 3; }
    }
    if (lane < 61) {                     // 500/4 = 125 float4s total
        float4 a = r4[64 + lane];
        int base = (64 + lane) * 4;
        if (a.x < m) { m = a.x; jm = base + 0; }
        if (a.y < m) { m = a.y; jm = base + 1; }
        if (a.z < m) { m = a.z; jm = base + 2; }
        if (a.w < m) { m = a.w; jm = base + 3; }
    }

    long long kb = __double_as_longlong((double)m) | (long long)jm;
    double kd = dpp_fmin_wave(__longlong_as_double(kb));
    if (lane == 63)
        rm[(size_t)b * NN + n] = kd;
}

// ---------------------------------------------------------------------------
// Kernel 2: per-batch rectangular LSA (JV / shortest augmenting path) on
// cost[b].T (N=128 rows x Q=500 cols). Row reduction + greedy init, then SAP.
// Round-6-validated algebra + round-10-validated simplifications:
//  - invalid columns fill with +INF: packed rp becomes NaN -> compares false,
//    removing all (k < nval) gates from the hot loops.
//  - no __syncthreads (single wave, lockstep; LDS ordered via lgkmcnt).
//  - f32 rows (2 KB/row) — f64 rows measured 2x slower (round 10).
// ONE WAVE per batch. Lane l owns columns j = 8l..8l+7 and rows l, l+64.
// ---------------------------------------------------------------------------
template <bool USE_CT, bool PRE>
__global__ __launch_bounds__(64) void lsa_wave_kernel(
    const float* __restrict__ C,    // (B,Q,N)
    const float* __restrict__ CT,   // (B,N,Q) or nullptr
    const double* __restrict__ rm,  // (B,N) packed rowmin or nullptr
    float* __restrict__ out_rows,   // (B,N) as float
    float* __restrict__ out_cols)   // (B,N) as float
{
#pragma clang fp contract(off)
    const int b = blockIdx.x;
    const int lane = threadIdx.x;

    __shared__ double s_spc[64 * 10];   // stride 10 doubles (80 B) per lane
    __shared__ int s_q[NN];

    const float* Cb  = C + (size_t)b * QQ * NN;
    const float* CTb = USE_CT ? (CT + (size_t)b * NN * QQ) : nullptr;

    const int j0 = lane * 8;
    const int nval = (QQ - j0 < 0) ? 0 : ((QQ - j0 > 8) ? 8 : (QQ - j0));

    double v_[8], spc_[8];
    int path_[8], r4c_[8];
    double u0, u1;
    int c4r0 = -1, c4r1 = -1;
    int jm0, jm1;
#pragma unroll
    for (int k = 0; k < 8; ++k) { v_[k] = 0.0; r4c_[k] = -1; }

    // ---- Phase A: row minima (u) from rowmin kernel + L2 warm pass ----
    if (PRE) {
        const long long p0 = __double_as_longlong(rm[(size_t)b * NN + lane]);
        const long long p1 = __double_as_longlong(rm[(size_t)b * NN + 64 + lane]);
        u0 = __longlong_as_double(p0 & ~0x1FFLL);
        u1 = __longlong_as_double(p1 & ~0x1FFLL);
        jm0 = (int)(p0 & 0x1FF);
        jm1 = (int)(p1 & 0x1FF);
        if (USE_CT) {
            // coalesced warm pass: pull this batch's CT slice into local L2
            const float4* w4 = reinterpret_cast<const float4*>(CTb);
            float4 acc; acc.x = acc.y = acc.z = acc.w = 0.0f;
#pragma unroll 8
            for (int t = lane; t < (NN * QQ) / 4; t += 64) {
                float4 a = w4[t];
                acc.x += a.x; acc.y += a.y; acc.z += a.z; acc.w += a.w;
            }
            asm volatile("" :: "v"(acc.x), "v"(acc.y), "v"(acc.z), "v"(acc.w));
        }
    } else {
        float m0 = INFINITY, m1 = INFINITY;
        jm0 = 0; jm1 = 0;
#pragma unroll 4
        for (int q = 0; q < QQ; ++q) {
            float a, c;
            if (USE_CT) {
                a = CTb[(size_t)lane * QQ + q];
                c = CTb[(size_t)(64 + lane) * QQ + q];
            } else {
                a = Cb[(size_t)q * NN + lane];
                c = Cb[(size_t)q * NN + 64 + lane];
            }
            if (a < m0) { m0 = a; jm0 = q; }
            if (c < m1) { m1 = c; jm1 = q; }
        }
        u0 = (double)m0;
        u1 = (double)m1;
    }

    // ---- Phase B: greedy matching on row minima (sequential, uniform) ----
    for (int i = 0; i < NN; ++i) {
        int jm = (i < 64) ? rl_i(jm0, i) : rl_i(jm1, i - 64);
        int kq = jm & 7;
        int selr; SEL8(r4c_, kq, selr);
        int occ = rl_i(selr, jm >> 3);
        if (occ < 0) {
            if (lane == (jm >> 3)) { SCAT8(r4c_, kq, i); }
            if (i < 64) { if (lane == i) c4r0 = jm; }
            else        { if (lane == i - 64) c4r1 = jm; }
        }
    }

    // ---- Phase C: shortest augmenting path for the unmatched rows ----
    for (int cur = 0; cur < NN; ++cur) {
        int already = (cur < 64) ? rl_i(c4r0, cur) : rl_i(c4r1, cur - 64);
        if (already >= 0) continue;

        const double INF = INFINITY;
#pragma unroll
        for (int k = 0; k < 8; ++k) { spc_[k] = INF; path_[k] = -1; }
        unsigned int sc = 0;
        int sr0 = 0, sr1 = 0;
        double minv = 0.0;
        int i = cur, sink = -1;

        while (true) {
            // ---- cost row i, my 8 columns (invalid -> +INF) ----
            double c_[8];
            if (USE_CT) {
                const float4* p = reinterpret_cast<const float4*>(CTb + (size_t)i * QQ + j0);
                if (nval > 0) {
                    float4 a = p[0];
                    c_[0] = (double)a.x; c_[1] = (double)a.y;
                    c_[2] = (double)a.z; c_[3] = (double)a.w;
                } else { c_[0] = c_[1] = c_[2] = c_[3] = INF; }
                if (nval > 4) {
                    float4 a = p[1];
                    c_[4] = (double)a.x; c_[5] = (double)a.y;
                    c_[6] = (double)a.z; c_[7] = (double)a.w;
                } else { c_[4] = c_[5] = c_[6] = c_[7] = INF; }
            } else {
#pragma unroll
                for (int k = 0; k < 8; ++k)
                    c_[k] = (j0 + k < QQ) ? (double)Cb[(size_t)(j0 + k) * NN + i] : INF;
            }

            // SR[i] = True
            if (i < 64) { if (lane == i) sr0 = 1; }
            else        { if (lane == i - 64) sr1 = 1; }

            // u[i] broadcast — uniform i => readlane
            double ui = (i < 64) ? rl_d(u0, i) : rl_d(u1, i - 64);
            double s = minv - ui;   // wave-uniform

            // relax + pack column index into low mantissa bits.
            // invalid k: c=+INF -> rp is NaN -> compare false (no nval gate).
#pragma unroll
            for (int k = 0; k < 8; ++k) {
                double r = (s + c_[k]) - v_[k];
                long long rb = (__double_as_longlong(r) & ~0x1FFLL)
                             | (long long)(j0 + k);
                double rp = __longlong_as_double(rb);
                bool ok = !((sc >> k) & 1) && (rp < spc_[k]);
                if (ok) { spc_[k] = rp; path_[k] = i; }
            }

            // local min: mask SC -> inf + pure fmin tree (invalid spc stay INF)
            double val[8];
#pragma unroll
            for (int k = 0; k < 8; ++k)
                val[k] = ((sc >> k) & 1) ? INF : spc_[k];
            double t01 = fmin(val[0], val[1]);
            double t23 = fmin(val[2], val[3]);
            double t45 = fmin(val[4], val[5]);
            double t67 = fmin(val[6], val[7]);
            double lmin = fmin(fmin(t01, t23), fmin(t45, t67));

            // wave min via DPP chain; lane 63 holds global packed min
            double gk = rl_d(dpp_fmin_wave(lmin), 63);

            int jmin   = (int)(__double_as_longlong(gk) & 0x1FFLL);
            int winner = jmin >> 3;

            // SC[jmin] = True
            if (lane == winner) sc |= 1u << (jmin & 7);

            // r4 = row4col[jmin]  (uniform => readlane)
            int kq = jmin & 7;
            int selr; SEL8(r4c_, kq, selr);
            int r4 = rl_i(selr, winner);

            minv = gk;              // == spc[jmin] exactly (packed)
            if (r4 < 0) { sink = jmin; break; }
            i = r4;
        }

        // ---- spill spc to LDS for the col4row gather (single wave:
        // lockstep + compiler lgkmcnt ordering; validated round 10) ----
        {
            double* base = s_spc + lane * 10;
            double2 d01; d01.x = spc_[0]; d01.y = spc_[1];
            double2 d23; d23.x = spc_[2]; d23.y = spc_[3];
            double2 d45; d45.x = spc_[4]; d45.y = spc_[5];
            double2 d67; d67.x = spc_[6]; d67.y = spc_[7];
            *(double2*)(base + 0) = d01;
            *(double2*)(base + 2) = d23;
            *(double2*)(base + 4) = d45;
            *(double2*)(base + 6) = d67;
        }
        const int g0i = (c4r0 < 0) ? 0 : c4r0;
        const int g1i = (c4r1 < 0) ? 0 : c4r1;
        const double g0 = s_spc[(g0i >> 3) * 10 + (g0i & 7)];
        const double g1 = s_spc[(g1i >> 3) * 10 + (g1i & 7)];

        // ---- dual updates (pre-augmentation col4row) ----
        if (lane == cur) { u0 = u0 + minv; }
        else if (sr0)    { double t = minv - g0; u0 = u0 + t; }
        if (lane + 64 == cur) { u1 = u1 + minv; }
        else if (sr1)         { double t = minv - g1; u1 = u1 + t; }
#pragma unroll
        for (int k = 0; k < 8; ++k) {
            if ((sc >> k) & 1) {
                double t = minv - spc_[k];
                v_[k] = v_[k] - t;
            }
        }

        // ---- augment along alternating path (uniform j walk, readlane) ----
        int j = sink;
        while (true) {
            int kq = j & 7, src = j >> 3;
            int sp; SEL8(path_, kq, sp);
            int i2 = rl_i(sp, src);
            if (lane == src) { SCAT8(r4c_, kq, i2); }   // row4col[j] = i2
            int t2;
            if (i2 < 64) {
                t2 = rl_i(c4r0, i2);
                if (lane == i2) c4r0 = j;
            } else {
                t2 = rl_i(c4r1, i2 - 64);
                if (lane == i2 - 64) c4r1 = j;
            }
            j = t2;
            if (i2 == cur) break;
        }
    }

    // ---- output: rows = sorted assigned-query idx, cols = target idx ----
    s_q[lane] = c4r0;
    s_q[64 + lane] = c4r1;
    int rank0 = 0, rank1 = 0;
    for (int t = 0; t < NN; ++t) {
        int qv = s_q[t];
        rank0 += (qv < c4r0) ? 1 : 0;
        rank1 += (qv < c4r1) ? 1 : 0;
    }
    out_rows[(size_t)b * NN + rank0] = (float)c4r0;
    out_cols[(size_t)b * NN + rank0] = (float)lane;
    out_rows[(size_t)b * NN + rank1] = (float)c4r1;
    out_cols[(size_t)b * NN + rank1] = (float)(64 + lane);
}

// ---------------------------------------------------------------------------
extern "C" void kernel_launch(void* const* d_in, const int* in_sizes, int n_in,
                              void* d_out, int out_size, void* d_ws, size_t ws_size,
                              hipStream_t stream) {
    const float* pb = (const float*)d_in[0];  // pred_boxes     (B,Q,4)
    const float* pk = (const float*)d_in[1];  // pred_keypoints (B,Q,17,2)
    const float* tb = (const float*)d_in[2];  // tgt_boxes      (B,N,4)
    const float* tk = (const float*)d_in[3];  // tgt_keypoints  (B,N,17,2)

    float* outC  = (float*)d_out;                      // (B,Q,N)
    float* orows = outC + (size_t)BB * QQ * NN;        // (B,N)
    float* ocols = orows + (size_t)BB * NN;            // (B,N)

    const size_t ct_bytes = (size_t)BB * NN * QQ * sizeof(float);  // 4,096,000
    const size_t rm_bytes = (size_t)BB * NN * sizeof(double);      //    16,384
    const bool useCT = (ws_size >= ct_bytes);
    const bool pre   = (ws_size >= ct_bytes + rm_bytes);
    float*  CT = useCT ? (float*)d_ws : nullptr;
    double* RM = pre ? (double*)((char*)d_ws + ct_bytes) : nullptr;

    dim3 grid(QQ, BB);
    cost_kernel<<<grid, 128, 0, stream>>>(pb, pk, tb, tk, outC, CT, useCT ? 1 : 0);

    if (pre) {
        rowmin_kernel<<<dim3(NN, BB), 64, 0, stream>>>(CT, RM);
        lsa_wave_kernel<true, true><<<BB, 64, 0, stream>>>(outC, CT, RM, orows, ocols);
    } else if (useCT) {
        lsa_wave_kernel<true, false><<<BB, 64, 0, stream>>>(outC, CT, nullptr, orows, ocols);
    } else {
        lsa_wave_kernel<false, false><<<BB, 64, 0, stream>>>(outC, nullptr, nullptr, orows, ocols);
    }
}

// Round 12
// 128.329 us; speedup vs baseline: 1.7965x; 1.0449x over previous
//
#include <hip/hip_runtime.h>
#include <math.h>

#define BB 16
#define QQ 500
#define NN 128
#define KK2 34   // 17 keypoints * 2

// ---------------------------------------------------------------------------
// Kernel 1: cost matrix  C[b][q][n]  (fp32, exact op order of the reference)
// Also writes transposed CT[b][n][q]. UNCHANGED (numerics must stay identical).
// ---------------------------------------------------------------------------
__global__ __launch_bounds__(128) void cost_kernel(
    const float* __restrict__ pb,   // (B,Q,4) cxcywh
    const float* __restrict__ pk,   // (B,Q,17,2)
    const float* __restrict__ tb,   // (B,N,4)
    const float* __restrict__ tk,   // (B,N,17,2)
    float* __restrict__ C,          // (B,Q,N)
    float* __restrict__ CT,         // (B,N,Q) or nullptr
    int writeCT)
{
#pragma clang fp contract(off)
    const int q = blockIdx.x;
    const int b = blockIdx.y;
    const int n = threadIdx.x;

    __shared__ float spb[4];
    __shared__ float spk[KK2];
    if (threadIdx.x < 4)
        spb[threadIdx.x] = pb[((size_t)b * QQ + q) * 4 + threadIdx.x];
    if (threadIdx.x < KK2)
        spk[threadIdx.x] = pk[((size_t)b * QQ + q) * KK2 + threadIdx.x];
    __syncthreads();

    const float pcx = spb[0], pcy = spb[1], pw = spb[2], ph = spb[3];

    const size_t tbase = ((size_t)b * NN + n) * 4;
    const float tcx = tb[tbase + 0];
    const float tcy = tb[tbase + 1];
    const float tw  = tb[tbase + 2];
    const float th  = tb[tbase + 3];

    float cb = fabsf(pcx - tcx);
    cb = cb + fabsf(pcy - tcy);
    cb = cb + fabsf(pw - tw);
    cb = cb + fabsf(ph - th);

    float px0 = pcx - 0.5f * pw;
    float py0 = pcy - 0.5f * ph;
    float px1 = pcx + 0.5f * pw;
    float py1 = pcy + 0.5f * ph;
    px1 = fmaxf(px1, px0 + 1e-4f);
    py1 = fmaxf(py1, py0 + 1e-4f);

    float tx0 = tcx - 0.5f * tw;
    float ty0 = tcy - 0.5f * th;
    float tx1 = tcx + 0.5f * tw;
    float ty1 = tcy + 0.5f * th;
    tx1 = fmaxf(tx1, tx0 + 1e-4f);
    ty1 = fmaxf(ty1, ty0 + 1e-4f);

    const float area_p = (px1 - px0) * (py1 - py0);
    const float area_t = (tx1 - tx0) * (ty1 - ty0);

    const float ltx = fmaxf(px0, tx0);
    const float lty = fmaxf(py0, ty0);
    const float rbx = fminf(px1, tx1);
    const float rby = fminf(py1, ty1);
    const float wx = fmaxf(rbx - ltx, 0.0f);
    const float wy = fmaxf(rby - lty, 0.0f);
    const float inter = wx * wy;
    const float uni = (area_p + area_t) - inter;
    const float iou = inter / uni;

    const float ex0 = fminf(px0, tx0);
    const float ey0 = fminf(py0, ty0);
    const float ex1 = fmaxf(px1, tx1);
    const float ey1 = fmaxf(py1, ty1);
    const float ewx = fmaxf(ex1 - ex0, 0.0f);
    const float ewy = fmaxf(ey1 - ey0, 0.0f);
    const float enc = ewx * ewy;

    const float giou = iou - (enc - uni) / enc;
    const float cg = -giou;

    const size_t kbase = ((size_t)b * NN + n) * KK2;
    float ck = 0.0f;
    for (int k = 0; k < KK2; ++k)
        ck = ck + fabsf(spk[k] - tk[kbase + k]);

    const float Cv = (5.0f * cb + 2.0f * cg) + ck;

    C[((size_t)b * QQ + q) * NN + n] = Cv;
    if (writeCT)
        CT[((size_t)b * NN + n) * QQ + q] = Cv;
}

// uniform-lane readlane helpers (scalar pipe, no LDS)
__device__ __forceinline__ int rl_i(int v, int l) {
    return __builtin_amdgcn_readlane(v, l);
}
__device__ __forceinline__ double rl_d(double v, int l) {
    int lo = __builtin_amdgcn_readlane(__double2loint(v), l);
    int hi = __builtin_amdgcn_readlane(__double2hiint(v), l);
    return __hiloint2double(hi, lo);
}

// one DPP min step on f64 (two 32-bit dpp movs + v_min_f64)
template <int CTRL>
__device__ __forceinline__ double dpp_fmin_step(double x) {
    int lo = __double2loint(x);
    int hi = __double2hiint(x);
    int nlo = __builtin_amdgcn_update_dpp(lo, lo, CTRL, 0xF, 0xF, false);
    int nhi = __builtin_amdgcn_update_dpp(hi, hi, CTRL, 0xF, 0xF, false);
    return fmin(__hiloint2double(nhi, nlo), x);
}
#define ROW_SHR1  0x111
#define ROW_SHR2  0x112
#define ROW_SHR4  0x114
#define ROW_SHR8  0x118
#define ROW_BC15  0x142
#define ROW_BC31  0x143

__device__ __forceinline__ double dpp_fmin_wave(double x) {
    x = dpp_fmin_step<ROW_SHR1>(x);
    x = dpp_fmin_step<ROW_SHR2>(x);
    x = dpp_fmin_step<ROW_SHR4>(x);
    x = dpp_fmin_step<ROW_SHR8>(x);
    x = dpp_fmin_step<ROW_BC15>(x);
    x = dpp_fmin_step<ROW_BC31>(x);
    return x;   // lane 63 holds the wave min
}

// constant-index select/scatter on 8-arrays (register-resident, rule #20)
#define SEL8(arr, kq, out) do { \
    out = arr[0]; \
    if ((kq)==1) out = arr[1]; if ((kq)==2) out = arr[2]; if ((kq)==3) out = arr[3]; \
    if ((kq)==4) out = arr[4]; if ((kq)==5) out = arr[5]; if ((kq)==6) out = arr[6]; \
    if ((kq)==7) out = arr[7]; } while (0)

#define SCAT8(arr, kq, val) do { \
    if ((kq)==0) arr[0] = (val); if ((kq)==1) arr[1] = (val); \
    if ((kq)==2) arr[2] = (val); if ((kq)==3) arr[3] = (val); \
    if ((kq)==4) arr[4] = (val); if ((kq)==5) arr[5] = (val); \
    if ((kq)==6) arr[6] = (val); if ((kq)==7) arr[7] = (val); } while (0)

// ---------------------------------------------------------------------------
// Kernel 1.5: per-row min + first-occurrence argmin of CT rows.
// One block (64 lanes) per (row, batch). Packs exact f64(min)|9-bit-index
// (f32->f64 leaves 29 zero mantissa bits; mask recovers u exactly).
// ---------------------------------------------------------------------------
__global__ __launch_bounds__(64) void rowmin_kernel(
    const float* __restrict__ CT,   // (B,N,Q)
    double* __restrict__ rm)        // (B,N) packed f64(min)|argmin
{
    const int n = blockIdx.x;
    const int b = blockIdx.y;
    const int lane = threadIdx.x;

    const float4* r4 = reinterpret_cast<const float4*>(CT + ((size_t)b * NN + n) * QQ);

    float m = INFINITY;
    int jm = 0;
    {
        float4 a = r4[lane];             // elements 4*lane .. 4*lane+3
        int base = lane * 4;
        if (a.x < m) { m = a.x; jm = base + 0; }
        if (a.y < m) { m = a.y; jm = base + 1; }
        if (a.z < m) { m = a.z; jm = base + 2; }
        if (a.w < m) { m = a.w; jm = base + 3; }
    }
    if (lane < 61) {                     // 500/4 = 125 float4s total
        float4 a = r4[64 + lane];
        int base = (64 + lane) * 4;
        if (a.x < m) { m = a.x; jm = base + 0; }
        if (a.y < m) { m = a.y; jm = base + 1; }
        if (a.z < m) { m = a.z; jm = base + 2; }
        if (a.w < m) { m = a.w; jm = base + 3; }
    }

    long long kb = __double_as_longlong((double)m) | (long long)jm;
    double kd = dpp_fmin_wave(__longlong_as_double(kb));
    if (lane == 63)
        rm[(size_t)b * NN + n] = kd;
}

// ---------------------------------------------------------------------------
// Kernel 2: per-batch rectangular LSA (JV / shortest augmenting path) on
// cost[b].T (N=128 rows x Q=500 cols). Row reduction + greedy init, then
// LAPJV augmenting-row-reduction (ARR), then SAP for leftover rows.
// Invariants maintained at every step: rc = C-u-v >= 0; matched edges tight;
// v <= 0 and every v<0 column is matched (rectangular-LP dual feasibility).
// -> final matching is the exact optimum == reference (unique optimum).
// ONE WAVE per batch. Lane l owns columns j = 8l..8l+7 and rows l, l+64.
// ---------------------------------------------------------------------------
template <bool USE_CT, bool PRE>
__global__ __launch_bounds__(64) void lsa_wave_kernel(
    const float* __restrict__ C,    // (B,Q,N)
    const float* __restrict__ CT,   // (B,N,Q) or nullptr
    const double* __restrict__ rm,  // (B,N) packed rowmin or nullptr
    float* __restrict__ out_rows,   // (B,N) as float
    float* __restrict__ out_cols)   // (B,N) as float
{
#pragma clang fp contract(off)
    const int b = blockIdx.x;
    const int lane = threadIdx.x;

    __shared__ double s_spc[64 * 10];   // stride 10 doubles (80 B) per lane
    __shared__ int s_q[NN];

    const float* Cb  = C + (size_t)b * QQ * NN;
    const float* CTb = USE_CT ? (CT + (size_t)b * NN * QQ) : nullptr;

    const int j0 = lane * 8;
    const int nval = (QQ - j0 < 0) ? 0 : ((QQ - j0 > 8) ? 8 : (QQ - j0));

    double v_[8], spc_[8];
    int path_[8], r4c_[8];
    double u0, u1;
    int c4r0 = -1, c4r1 = -1;
    int jm0, jm1;
#pragma unroll
    for (int k = 0; k < 8; ++k) { v_[k] = 0.0; r4c_[k] = -1; }

    // ---- Phase A: row minima (u) from rowmin kernel + L2 warm pass ----
    if (PRE) {
        const long long p0 = __double_as_longlong(rm[(size_t)b * NN + lane]);
        const long long p1 = __double_as_longlong(rm[(size_t)b * NN + 64 + lane]);
        u0 = __longlong_as_double(p0 & ~0x1FFLL);
        u1 = __longlong_as_double(p1 & ~0x1FFLL);
        jm0 = (int)(p0 & 0x1FF);
        jm1 = (int)(p1 & 0x1FF);
        if (USE_CT) {
            // coalesced warm pass: pull this batch's CT slice into local L2
            const float4* w4 = reinterpret_cast<const float4*>(CTb);
            float4 acc; acc.x = acc.y = acc.z = acc.w = 0.0f;
#pragma unroll 8
            for (int t = lane; t < (NN * QQ) / 4; t += 64) {
                float4 a = w4[t];
                acc.x += a.x; acc.y += a.y; acc.z += a.z; acc.w += a.w;
            }
            asm volatile("" :: "v"(acc.x), "v"(acc.y), "v"(acc.z), "v"(acc.w));
        }
    } else {
        float m0 = INFINITY, m1 = INFINITY;
        jm0 = 0; jm1 = 0;
#pragma unroll 4
        for (int q = 0; q < QQ; ++q) {
            float a, c;
            if (USE_CT) {
                a = CTb[(size_t)lane * QQ + q];
                c = CTb[(size_t)(64 + lane) * QQ + q];
            } else {
                a = Cb[(size_t)q * NN + lane];
                c = Cb[(size_t)q * NN + 64 + lane];
            }
            if (a < m0) { m0 = a; jm0 = q; }
            if (c < m1) { m1 = c; jm1 = q; }
        }
        u0 = (double)m0;
        u1 = (double)m1;
    }

    // ---- Phase B: greedy matching on row minima (sequential, uniform) ----
    for (int i = 0; i < NN; ++i) {
        int jm = (i < 64) ? rl_i(jm0, i) : rl_i(jm1, i - 64);
        int kq = jm & 7;
        int selr; SEL8(r4c_, kq, selr);
        int occ = rl_i(selr, jm >> 3);
        if (occ < 0) {
            if (lane == (jm >> 3)) { SCAT8(r4c_, kq, i); }
            if (i < 64) { if (lane == i) c4r0 = jm; }
            else        { if (lane == i - 64) c4r1 = jm; }
        }
    }

    // ---- Phase B2: augmenting row reduction (LAPJV ARR) ----
    // For each free row: (m1,j1,m2) over t_j = C(i,j) - v_j.
    // m1<m2: u[i]=m2, v[j1]-=(m2-m1) (v only DECREASES -> rectangular-valid),
    // take j1 (displaced owner continues the chain). m1==m2 & j1 taken: leave
    // for SAP with refreshed u[i]=m1 (still feasible). Step cap -> SAP fallback.
    if (USE_CT) {
        unsigned long long fr0 = __ballot(c4r0 < 0);
        unsigned long long fr1 = __ballot(c4r1 < 0);
        int steps = 0;
        int i = -1;
        while (steps < 192) {
            if (i < 0) {
                if (fr0)      { i = __ffsll((long long)fr0) - 1; fr0 &= fr0 - 1; }
                else if (fr1) { i = 64 + (__ffsll((long long)fr1) - 1); fr1 &= fr1 - 1; }
                else break;
            }
            ++steps;
            // row i, my 8 columns (coalesced float4 from CT; L2-warm)
            float c_[8];
            {
                const float4* p = reinterpret_cast<const float4*>(CTb + (size_t)i * QQ + j0);
                if (nval > 0) { float4 a = p[0]; c_[0]=a.x; c_[1]=a.y; c_[2]=a.z; c_[3]=a.w; }
                else { c_[0]=c_[1]=c_[2]=c_[3]=0.0f; }
                if (nval > 4) { float4 a = p[1]; c_[4]=a.x; c_[5]=a.y; c_[6]=a.z; c_[7]=a.w; }
                else { c_[4]=c_[5]=c_[6]=c_[7]=0.0f; }
            }
            // lane-local two smallest of t (exact f64) + local argmin
            double m1 = INFINITY, m2 = INFINITY; int jl = 0;
#pragma unroll
            for (int k = 0; k < 8; ++k) {
                double t = (k < nval) ? ((double)c_[k] - v_[k]) : INFINITY;
                bool lt1 = t < m1;
                m2 = lt1 ? m1 : fmin(m2, t);
                jl = lt1 ? (j0 + k) : jl;
                m1 = lt1 ? t : m1;
            }
            // exact wave min1 + first-occurrence winner (ballot, no packing)
            double g1 = rl_d(dpp_fmin_wave(m1), 63);
            unsigned long long bl = __ballot(m1 == g1);
            int winner = __ffsll((long long)bl) - 1;
            int j1 = rl_i(jl, winner);
            // wave min2 = min( m2[winner], m1[lane != winner] )
            double a2 = (lane == winner) ? m2 : m1;
            double g2 = rl_d(dpp_fmin_wave(a2), 63);
            // owner of column j1
            int kq = j1 & 7;
            int selr; SEL8(r4c_, kq, selr);
            int i0 = rl_i(selr, j1 >> 3);

            if (g1 < g2) {
                // u[i]=g2; v[j1]-=(g2-g1); match i->j1 (tight: rc=0 exactly)
                if (i < 64) { if (lane == i) { u0 = g2; c4r0 = j1; } }
                else        { if (lane == i - 64) { u1 = g2; c4r1 = j1; } }
                if (lane == (j1 >> 3)) {
                    double vv; SEL8(v_, kq, vv);
                    vv = vv - (g2 - g1);
                    SCAT8(v_, kq, vv);
                    SCAT8(r4c_, kq, i);
                }
                if (i0 >= 0) {
                    if (i0 < 64) { if (lane == i0) c4r0 = -1; }
                    else         { if (lane == i0 - 64) c4r1 = -1; }
                    i = i0;        // displaced row continues the chain
                } else {
                    i = -1;        // matched a free column; next free row
                }
            } else {
                if (i0 < 0) {
                    // exact tie but j1 free: u[i]=g1, match (tight, no v change)
                    if (i < 64) { if (lane == i) { u0 = g1; c4r0 = j1; } }
                    else        { if (lane == i - 64) { u1 = g1; c4r1 = j1; } }
                    if (lane == (j1 >> 3)) { SCAT8(r4c_, kq, i); }
                } else {
                    // leave row free for SAP; refresh u[i]=g1 (rc >= 0 kept)
                    if (i < 64) { if (lane == i) u0 = g1; }
                    else        { if (lane == i - 64) u1 = g1; }
                }
                i = -1;
            }
        }
    }

    // ---- Phase C: shortest augmenting path for remaining free rows ----
    // (round-6-validated packed-spc implementation, verbatim)
    for (int cur = 0; cur < NN; ++cur) {
        int already = (cur < 64) ? rl_i(c4r0, cur) : rl_i(c4r1, cur - 64);
        if (already >= 0) continue;

        const double INF = INFINITY;
#pragma unroll
        for (int k = 0; k < 8; ++k) { spc_[k] = INF; path_[k] = -1; }
        unsigned int sc = 0;
        int sr0 = 0, sr1 = 0;
        double minv = 0.0;
        int i = cur, sink = -1;

        while (true) {
            // ---- cost row i, my 8 columns (coalesced float4 from CT) ----
            float c_[8];
            if (USE_CT) {
                const float4* p = reinterpret_cast<const float4*>(CTb + (size_t)i * QQ + j0);
                if (nval > 0) {
                    float4 a = p[0];
                    c_[0] = a.x; c_[1] = a.y; c_[2] = a.z; c_[3] = a.w;
                } else { c_[0] = c_[1] = c_[2] = c_[3] = 0.0f; }
                if (nval > 4) {
                    float4 a = p[1];
                    c_[4] = a.x; c_[5] = a.y; c_[6] = a.z; c_[7] = a.w;
                } else { c_[4] = c_[5] = c_[6] = c_[7] = 0.0f; }
            } else {
#pragma unroll
                for (int k = 0; k < 8; ++k)
                    c_[k] = (j0 + k < QQ) ? Cb[(size_t)(j0 + k) * NN + i] : 0.0f;
            }

            // SR[i] = True
            if (i < 64) { if (lane == i) sr0 = 1; }
            else        { if (lane == i - 64) sr1 = 1; }

            // u[i] broadcast — uniform i => readlane
            double ui = (i < 64) ? rl_d(u0, i) : rl_d(u1, i - 64);
            double s = minv - ui;   // wave-uniform

            // relax + pack column index into low mantissa bits
#pragma unroll
            for (int k = 0; k < 8; ++k) {
                double r = (s + (double)c_[k]) - v_[k];
                long long rb = (__double_as_longlong(r) & ~0x1FFLL)
                             | (long long)(j0 + k);
                double rp = __longlong_as_double(rb);
                bool ok = (k < nval) && !((sc >> k) & 1) && (rp < spc_[k]);
                if (ok) { spc_[k] = rp; path_[k] = i; }
            }

            // local min: mask (SC/invalid -> inf) + pure fmin tree (no idx sel)
            double val[8];
#pragma unroll
            for (int k = 0; k < 8; ++k) {
                bool okk = (k < nval) && !((sc >> k) & 1);
                val[k] = okk ? spc_[k] : INF;
            }
            double t01 = fmin(val[0], val[1]);
            double t23 = fmin(val[2], val[3]);
            double t45 = fmin(val[4], val[5]);
            double t67 = fmin(val[6], val[7]);
            double lmin = fmin(fmin(t01, t23), fmin(t45, t67));

            // wave min via DPP chain; lane 63 holds global packed min
            double gk = rl_d(dpp_fmin_wave(lmin), 63);

            int jmin   = (int)(__double_as_longlong(gk) & 0x1FFLL);
            int winner = jmin >> 3;

            // SC[jmin] = True
            if (lane == winner) sc |= 1u << (jmin & 7);

            // r4 = row4col[jmin]  (uniform => readlane)
            int kq = jmin & 7;
            int selr; SEL8(r4c_, kq, selr);
            int r4 = rl_i(selr, winner);

            minv = gk;              // == spc[jmin] exactly (packed)
            if (r4 < 0) { sink = jmin; break; }
            i = r4;
        }

        // ---- spill spc to LDS for the col4row gather ----
        {
            double* base = s_spc + lane * 10;
            double2 d01; d01.x = spc_[0]; d01.y = spc_[1];
            double2 d23; d23.x = spc_[2]; d23.y = spc_[3];
            double2 d45; d45.x = spc_[4]; d45.y = spc_[5];
            double2 d67; d67.x = spc_[6]; d67.y = spc_[7];
            *(double2*)(base + 0) = d01;
            *(double2*)(base + 2) = d23;
            *(double2*)(base + 4) = d45;
            *(double2*)(base + 6) = d67;
        }
        __syncthreads();
        const int g0i = (c4r0 < 0) ? 0 : c4r0;
        const int g1i = (c4r1 < 0) ? 0 : c4r1;
        const double g0 = s_spc[(g0i >> 3) * 10 + (g0i & 7)];
        const double g1 = s_spc[(g1i >> 3) * 10 + (g1i & 7)];

        // ---- dual updates (pre-augmentation col4row) ----
        if (lane == cur) { u0 = u0 + minv; }
        else if (sr0)    { double t = minv - g0; u0 = u0 + t; }
        if (lane + 64 == cur) { u1 = u1 + minv; }
        else if (sr1)         { double t = minv - g1; u1 = u1 + t; }
#pragma unroll
        for (int k = 0; k < 8; ++k) {
            if ((k < nval) && ((sc >> k) & 1)) {
                double t = minv - spc_[k];
                v_[k] = v_[k] - t;
            }
        }
        __syncthreads();   // spc LDS region reused next augmentation

        // ---- augment along alternating path (uniform j walk, readlane) ----
        int j = sink;
        while (true) {
            int kq = j & 7, src = j >> 3;
            int sp; SEL8(path_, kq, sp);
            int i2 = rl_i(sp, src);
            if (lane == src) { SCAT8(r4c_, kq, i2); }   // row4col[j] = i2
            int t2;
            if (i2 < 64) {
                t2 = rl_i(c4r0, i2);
                if (lane == i2) c4r0 = j;
            } else {
                t2 = rl_i(c4r1, i2 - 64);
                if (lane == i2 - 64) c4r1 = j;
            }
            j = t2;
            if (i2 == cur) break;
        }
    }

    // ---- output: rows = sorted assigned-query idx, cols = target idx ----
    s_q[lane] = c4r0;
    s_q[64 + lane] = c4r1;
    __syncthreads();
    int rank0 = 0, rank1 = 0;
    for (int t = 0; t < NN; ++t) {
        int qv = s_q[t];
        rank0 += (qv < c4r0) ? 1 : 0;
        rank1 += (qv < c4r1) ? 1 : 0;
    }
    out_rows[(size_t)b * NN + rank0] = (float)c4r0;
    out_cols[(size_t)b * NN + rank0] = (float)lane;
    out_rows[(size_t)b * NN + rank1] = (float)c4r1;
    out_cols[(size_t)b * NN + rank1] = (float)(64 + lane);
}

// ---------------------------------------------------------------------------
extern "C" void kernel_launch(void* const* d_in, const int* in_sizes, int n_in,
                              void* d_out, int out_size, void* d_ws, size_t ws_size,
                              hipStream_t stream) {
    const float* pb = (const float*)d_in[0];  // pred_boxes     (B,Q,4)
    const float* pk = (const float*)d_in[1];  // pred_keypoints (B,Q,17,2)
    const float* tb = (const float*)d_in[2];  // tgt_boxes      (B,N,4)
    const float* tk = (const float*)d_in[3];  // tgt_keypoints  (B,N,17,2)

    float* outC  = (float*)d_out;                      // (B,Q,N)
    float* orows = outC + (size_t)BB * QQ * NN;        // (B,N)
    float* ocols = orows + (size_t)BB * NN;            // (B,N)

    const size_t ct_bytes = (size_t)BB * NN * QQ * sizeof(float);  // 4,096,000
    const size_t rm_bytes = (size_t)BB * NN * sizeof(double);      //    16,384
    const bool useCT = (ws_size >= ct_bytes);
    const bool pre   = (ws_size >= ct_bytes + rm_bytes);
    float*  CT = useCT ? (float*)d_ws : nullptr;
    double* RM = pre ? (double*)((char*)d_ws + ct_bytes) : nullptr;

    dim3 grid(QQ, BB);
    cost_kernel<<<grid, 128, 0, stream>>>(pb, pk, tb, tk, outC, CT, useCT ? 1 : 0);

    if (pre) {
        rowmin_kernel<<<dim3(NN, BB), 64, 0, stream>>>(CT, RM);
        lsa_wave_kernel<true, true><<<BB, 64, 0, stream>>>(outC, CT, RM, orows, ocols);
    } else if (useCT) {
        lsa_wave_kernel<true, false><<<BB, 64, 0, stream>>>(outC, CT, nullptr, orows, ocols);
    } else {
        lsa_wave_kernel<false, false><<<BB, 64, 0, stream>>>(outC, nullptr, nullptr, orows, ocols);
    }
}